// Round 1
// baseline (1920.995 us; speedup 1.0000x reference)
//
#include <hip/hip_runtime.h>
#include <math.h>

static constexpr int F     = 64;
static constexpr int GRIDV = 64;
static constexpr int SEG   = 16 * GRIDV * GRIDV;   // 65536 clusters
static constexpr int SORT_CAP = 2048;

__device__ __forceinline__ float wave_min(float v) {
    for (int o = 32; o > 0; o >>= 1) v = fminf(v, __shfl_down(v, o));
    return v;
}
__device__ __forceinline__ float wave_max(float v) {
    for (int o = 32; o > 0; o >>= 1) v = fmaxf(v, __shfl_down(v, o));
    return v;
}

// ---- init: header + zero the 4 counter arrays (contiguous) ----
__global__ void k_init(unsigned* hdr, unsigned* cnts, int ncnt) {
    int i = blockIdx.x * blockDim.x + threadIdx.x;
    if (i == 0) { hdr[0] = 0x7F800000u; hdr[1] = 0x7F800000u; hdr[2] = 0u; }
    int stride = gridDim.x * blockDim.x;
    for (int j = i; j < ncnt; j += stride) cnts[j] = 0u;
}

// ---- global min of pos (per coordinate); values are >=0 so int atomicMin works
__global__ void k_min(const float2* pos, int n, unsigned* hdr) {
    int stride = gridDim.x * blockDim.x;
    float mx = INFINITY, my = INFINITY;
    for (int i = blockIdx.x * blockDim.x + threadIdx.x; i < n; i += stride) {
        float2 p = pos[i];
        mx = fminf(mx, p.x); my = fminf(my, p.y);
    }
    mx = wave_min(mx); my = wave_min(my);
    if ((threadIdx.x & 63) == 0) {
        atomicMin((int*)&hdr[0], __float_as_int(mx));
        atomicMin((int*)&hdr[1], __float_as_int(my));
    }
}

// ---- per-node cluster id + histogram ----
__global__ void k_cluster(const float2* pos, const int* batch, int n,
                          const unsigned* hdr, int* cl, unsigned* node_cnt) {
    int i = blockIdx.x * blockDim.x + threadIdx.x;
    if (i >= n) return;
    float sx = __int_as_float((int)hdr[0]);
    float sy = __int_as_float((int)hdr[1]);
    float2 p = pos[i];
    // division by VOXEL_SIZE = 2^-6 is exactly multiplication by 64
    int vx = (int)floorf((p.x - sx) * 64.0f);
    int vy = (int)floorf((p.y - sy) * 64.0f);
    vx = min(max(vx, 0), GRIDV - 1);
    vy = min(max(vy, 0), GRIDV - 1);
    int c = batch[i] * (GRIDV * GRIDV) + vy * GRIDV + vx;
    cl[i] = c;
    atomicAdd(&node_cnt[c], 1u);
}

// ---- exclusive scan over SEG counters (single block, 1024 threads) ----
__global__ void k_scan(const unsigned* cnt, unsigned* off, int n) {
    __shared__ unsigned sh[1024];
    __shared__ unsigned carry;
    int t = threadIdx.x;
    if (t == 0) carry = 0;
    __syncthreads();
    for (int base = 0; base < n; base += 1024) {
        unsigned v = (base + t < n) ? cnt[base + t] : 0u;
        sh[t] = v; __syncthreads();
        for (int s = 1; s < 1024; s <<= 1) {
            unsigned u = (t >= s) ? sh[t - s] : 0u;
            __syncthreads();
            sh[t] += u;
            __syncthreads();
        }
        unsigned incl = sh[t];
        if (base + t < n) off[base + t] = carry + incl - v;
        __syncthreads();
        if (t == 1023) carry += incl;
        __syncthreads();
    }
    if (t == 0) off[n] = carry;
}

// ---- scatter nodes into cluster-sorted order (unstable) ----
__global__ void k_scatter_nodes(const int* cl, int n, const unsigned* off,
                                unsigned* cur, int* node_sorted) {
    int i = blockIdx.x * blockDim.x + threadIdx.x;
    if (i >= n) return;
    int c = cl[i];
    unsigned slot = off[c] + atomicAdd(&cur[c], 1u);
    node_sorted[slot] = i;
}

// ---- pooled features (exact max) + mean positions; 1 wave per cluster ----
__global__ void k_pool(const float* __restrict__ x, const float* __restrict__ pos,
                       const int* __restrict__ node_sorted, const unsigned* __restrict__ off,
                       float* __restrict__ out_x, float* __restrict__ out_pos) {
    int s = blockIdx.x;
    int t = threadIdx.x;
    unsigned beg = off[s], end = off[s + 1];
    float m = -INFINITY;
    float ps = 0.f;
    for (unsigned idx = beg; idx < end; ++idx) {
        int nd = node_sorted[idx];
        m = fmaxf(m, x[(size_t)nd * F + t]);
        if (t < 2) ps += pos[(size_t)nd * 2 + t];
    }
    int cnt = (int)(end - beg);
    out_x[(size_t)s * F + t] = (cnt > 0) ? m : 0.f;
    if (t < 2) out_pos[s * 2 + t] = (cnt > 0) ? ps / (float)cnt : 0.f;
}

// ---- edge keys (r<<16|c) + histogram over r ----
__global__ void k_ehist(const int* __restrict__ ei, int e, const int* __restrict__ cl,
                        unsigned* __restrict__ keys_tmp, unsigned* __restrict__ ecnt) {
    int i = blockIdx.x * blockDim.x + threadIdx.x;
    if (i >= e) return;
    unsigned r = (unsigned)cl[ei[i]];
    unsigned c = (unsigned)cl[ei[e + i]];
    keys_tmp[i] = (r << 16) | c;
    atomicAdd(&ecnt[r], 1u);
}

// ---- scatter edges into r-bins (unstable) ----
__global__ void k_scatter_edges(const unsigned* __restrict__ keys_tmp, int e,
                                const unsigned* __restrict__ off, unsigned* cur,
                                unsigned* __restrict__ keys_sorted) {
    int i = blockIdx.x * blockDim.x + threadIdx.x;
    if (i >= e) return;
    unsigned k = keys_tmp[i];
    unsigned r = k >> 16;
    unsigned slot = off[r] + atomicAdd(&cur[r], 1u);
    keys_sorted[slot] = k;
}

// ---- sort each r-segment by full key (bitonic in LDS) ----
__global__ void k_segsort(unsigned* keys, const unsigned* __restrict__ off) {
    __shared__ unsigned sh[SORT_CAP];
    int s = blockIdx.x;
    int beg = (int)off[s], end = (int)off[s + 1];
    int len = end - beg;
    if (len <= 1) return;
    int t = threadIdx.x;
    if (len <= SORT_CAP) {
        int P = 2; while (P < len) P <<= 1;
        for (int i = t; i < P; i += blockDim.x)
            sh[i] = (i < len) ? keys[beg + i] : 0xFFFFFFFFu;
        __syncthreads();
        for (int k = 2; k <= P; k <<= 1) {
            for (int j = k >> 1; j > 0; j >>= 1) {
                for (int i = t; i < P; i += blockDim.x) {
                    int p = i ^ j;
                    if (p > i) {
                        unsigned a = sh[i], b = sh[p];
                        bool up = ((i & k) == 0);
                        if (up ? (a > b) : (a < b)) { sh[i] = b; sh[p] = a; }
                    }
                }
                __syncthreads();
            }
        }
        for (int i = t; i < len; i += blockDim.x) keys[beg + i] = sh[i];
    } else {
        // statistically unreachable fallback (segment > 2048): insertion sort
        if (t == 0) {
            for (int a = beg + 1; a < end; ++a) {
                unsigned v = keys[a]; int b = a - 1;
                while (b >= beg && keys[b] > v) { keys[b + 1] = keys[b]; --b; }
                keys[b + 1] = v;
            }
        }
    }
}

// ---- flags + e_row/e_col/edge_valid outputs + global max|cart| ----
__global__ void k_eflags(const unsigned* __restrict__ keys, int e,
                         const float2* __restrict__ pos_pool,
                         float* __restrict__ out_erow, float* __restrict__ out_ecol,
                         float* __restrict__ out_valid, unsigned* hdr) {
    int i = blockIdx.x * blockDim.x + threadIdx.x;
    float am = 0.f;
    if (i < e) {
        unsigned k = keys[i];
        bool first = (i == 0) || (k != keys[i - 1]);
        unsigned r = k >> 16, c = k & 0xFFFFu;
        bool valid = first && (r != c);
        out_erow[i]  = valid ? (float)r : 0.f;
        out_ecol[i]  = valid ? (float)c : 0.f;
        out_valid[i] = valid ? 1.f : 0.f;
        if (valid) {
            float2 pr = pos_pool[r], pc = pos_pool[c];
            am = fmaxf(fabsf(pr.x - pc.x), fabsf(pr.y - pc.y));
        }
    }
    am = wave_max(am);
    if ((threadIdx.x & 63) == 0) atomicMax((int*)&hdr[2], __float_as_int(am));
}

// ---- edge_attr = cart / (2*max) + 0.5 ----
__global__ void k_eattr(const unsigned* __restrict__ keys, int e,
                        const float2* __restrict__ pos_pool,
                        const unsigned* __restrict__ hdr, float* __restrict__ out_attr) {
    int i = blockIdx.x * blockDim.x + threadIdx.x;
    if (i >= e) return;
    unsigned k = keys[i];
    bool first = (i == 0) || (k != keys[i - 1]);
    unsigned r = k >> 16, c = k & 0xFFFFu;
    bool valid = first && (r != c);
    float ax = 0.f, ay = 0.f;
    if (valid) {
        float2 pr = pos_pool[r], pc = pos_pool[c];
        float denom = 2.0f * __int_as_float((int)hdr[2]);
        ax = (pr.x - pc.x) / denom + 0.5f;
        ay = (pr.y - pc.y) / denom + 0.5f;
    }
    out_attr[(size_t)i * 2]     = ax;
    out_attr[(size_t)i * 2 + 1] = ay;
}

extern "C" void kernel_launch(void* const* d_in, const int* in_sizes, int n_in,
                              void* d_out, int out_size, void* d_ws, size_t ws_size,
                              hipStream_t stream) {
    const float* x    = (const float*)d_in[0];
    const float* pos  = (const float*)d_in[1];
    const int* batch  = (const int*)d_in[2];
    const int* ei     = (const int*)d_in[3];
    const int n = in_sizes[2];
    const int e = in_sizes[3] / 2;

    float* out      = (float*)d_out;
    float* out_x    = out;                                   // [SEG, F]
    float* out_pos  = out_x  + (size_t)SEG * F;              // [SEG, 2]
    float* out_erow = out_pos + (size_t)SEG * 2;             // [E]
    float* out_ecol = out_erow + e;                          // [E]
    float* out_attr = out_ecol + e;                          // [E, 2]
    float* out_val  = out_attr + (size_t)2 * e;              // [E]

    char* w = (char*)d_ws;
    unsigned* hdr         = (unsigned*)w;                            // 3 u32 (pad 256)
    int*      cl          = (int*)(w + 256);                         // [n]
    int*      node_sorted = (int*)(w + 256 + (size_t)n * 4);         // [n]
    unsigned* node_cnt    = (unsigned*)(w + 256 + (size_t)n * 8);    // [SEG]
    unsigned* node_cur    = node_cnt + SEG;                          // [SEG]
    unsigned* ecnt        = node_cur + SEG;                          // [SEG]
    unsigned* ecur        = ecnt + SEG;                              // [SEG]
    unsigned* node_off    = ecur + SEG;                              // [SEG+1]
    unsigned* eoff        = node_off + SEG + 1;                      // [SEG+1]
    unsigned* keys_tmp    = eoff + SEG + 1;                          // [e]
    unsigned* keys_sorted = keys_tmp + e;                            // [e]

    const int nb_n = (n + 255) / 256;
    const int nb_e = (e + 255) / 256;

    k_init<<<512, 256, 0, stream>>>(hdr, node_cnt, 4 * SEG);
    k_min<<<1024, 256, 0, stream>>>((const float2*)pos, n, hdr);
    k_cluster<<<nb_n, 256, 0, stream>>>((const float2*)pos, batch, n, hdr, cl, node_cnt);
    k_scan<<<1, 1024, 0, stream>>>(node_cnt, node_off, SEG);
    k_scatter_nodes<<<nb_n, 256, 0, stream>>>(cl, n, node_off, node_cur, node_sorted);
    k_pool<<<SEG, 64, 0, stream>>>(x, pos, node_sorted, node_off, out_x, out_pos);
    k_ehist<<<nb_e, 256, 0, stream>>>(ei, e, cl, keys_tmp, ecnt);
    k_scan<<<1, 1024, 0, stream>>>(ecnt, eoff, SEG);
    k_scatter_edges<<<nb_e, 256, 0, stream>>>(keys_tmp, e, eoff, ecur, keys_sorted);
    k_segsort<<<SEG, 256, 0, stream>>>(keys_sorted, eoff);
    k_eflags<<<nb_e, 256, 0, stream>>>(keys_sorted, e, (const float2*)out_pos,
                                       out_erow, out_ecol, out_val, hdr);
    k_eattr<<<nb_e, 256, 0, stream>>>(keys_sorted, e, (const float2*)out_pos,
                                      hdr, out_attr);
}

// Round 2
// 836.376 us; speedup vs baseline: 2.2968x; 2.2968x over previous
//
#include <hip/hip_runtime.h>
#include <math.h>

static constexpr int F     = 64;
static constexpr int GRIDV = 64;
static constexpr int SEG   = 16 * GRIDV * GRIDV;   // 65536 clusters
static constexpr int SORT_CAP = 512;               // max edges per r-segment (stat. bound ~150)
static constexpr int MINB  = 1024;                 // blocks for k_min

__device__ __forceinline__ float wave_min(float v) {
    for (int o = 32; o > 0; o >>= 1) v = fminf(v, __shfl_down(v, o));
    return v;
}
__device__ __forceinline__ float wave_max(float v) {
    for (int o = 32; o > 0; o >>= 1) v = fmaxf(v, __shfl_down(v, o));
    return v;
}

// ---- zero the 4 counter arrays (contiguous) ----
__global__ void k_init(unsigned* cnts, int ncnt) {
    int i = blockIdx.x * blockDim.x + threadIdx.x;
    int stride = gridDim.x * blockDim.x;
    for (int j = i; j < ncnt; j += stride) cnts[j] = 0u;
}

// ---- per-block partial min of pos (no atomics) ----
__global__ void k_min(const float2* __restrict__ pos, int n, float2* __restrict__ pmin) {
    __shared__ float shx[4], shy[4];
    int stride = gridDim.x * blockDim.x;
    float mx = INFINITY, my = INFINITY;
    for (int i = blockIdx.x * blockDim.x + threadIdx.x; i < n; i += stride) {
        float2 p = pos[i];
        mx = fminf(mx, p.x); my = fminf(my, p.y);
    }
    mx = wave_min(mx); my = wave_min(my);
    int w = threadIdx.x >> 6;
    if ((threadIdx.x & 63) == 0) { shx[w] = mx; shy[w] = my; }
    __syncthreads();
    if (threadIdx.x == 0) {
        mx = fminf(fminf(shx[0], shx[1]), fminf(shx[2], shx[3]));
        my = fminf(fminf(shy[0], shy[1]), fminf(shy[2], shy[3]));
        pmin[blockIdx.x] = make_float2(mx, my);
    }
}

// ---- final min reduce: 1 block ----
__global__ void k_minred(const float2* __restrict__ pmin, int nb, unsigned* hdr) {
    __shared__ float shx[16], shy[16];
    int t = threadIdx.x;
    float mx = INFINITY, my = INFINITY;
    for (int i = t; i < nb; i += blockDim.x) {
        float2 p = pmin[i];
        mx = fminf(mx, p.x); my = fminf(my, p.y);
    }
    mx = wave_min(mx); my = wave_min(my);
    int w = t >> 6;
    if ((t & 63) == 0) { shx[w] = mx; shy[w] = my; }
    __syncthreads();
    if (t == 0) {
        int nw = (blockDim.x + 63) >> 6;
        for (int i = 1; i < nw; ++i) { mx = fminf(mx, shx[i]); my = fminf(my, shy[i]); }
        hdr[0] = (unsigned)__float_as_int(mx);
        hdr[1] = (unsigned)__float_as_int(my);
    }
}

// ---- per-node cluster id + histogram ----
__global__ void k_cluster(const float2* __restrict__ pos, const int* __restrict__ batch, int n,
                          const unsigned* __restrict__ hdr, int* __restrict__ cl,
                          unsigned* __restrict__ node_cnt) {
    int i = blockIdx.x * blockDim.x + threadIdx.x;
    if (i >= n) return;
    float sx = __int_as_float((int)hdr[0]);
    float sy = __int_as_float((int)hdr[1]);
    float2 p = pos[i];
    int vx = (int)floorf((p.x - sx) * 64.0f);   // /VOXEL_SIZE == *64 exactly
    int vy = (int)floorf((p.y - sy) * 64.0f);
    vx = min(max(vx, 0), GRIDV - 1);
    vy = min(max(vy, 0), GRIDV - 1);
    int c = batch[i] * (GRIDV * GRIDV) + vy * GRIDV + vx;
    cl[i] = c;
    atomicAdd(&node_cnt[c], 1u);
}

// ---- hierarchical exclusive scan over 65536 counters ----
// stage 1: 64 blocks x 1024; per-block inclusive scan, local exclusive out, block sums
__global__ void k_scan1(const unsigned* __restrict__ cnt, unsigned* __restrict__ off,
                        unsigned* __restrict__ blksum) {
    __shared__ unsigned sh[1024];
    int t = threadIdx.x;
    int g = blockIdx.x * 1024 + t;
    unsigned v = cnt[g];
    sh[t] = v;
    __syncthreads();
    for (int s = 1; s < 1024; s <<= 1) {
        unsigned u = (t >= s) ? sh[t - s] : 0u;
        __syncthreads();
        sh[t] += u;
        __syncthreads();
    }
    off[g] = sh[t] - v;
    if (t == 1023) blksum[blockIdx.x] = sh[1023];
}

// stage 2: add block bases (computed redundantly per block via wave prefix); write total
__global__ void k_scan_add(unsigned* __restrict__ off, const unsigned* __restrict__ blksum,
                           int n, unsigned total) {
    __shared__ unsigned base_sh;
    int t = threadIdx.x, b = blockIdx.x;
    if (t < 64) {
        unsigned v = (t < b) ? blksum[t] : 0u;
        for (int o = 32; o > 0; o >>= 1) v += __shfl_down(v, o);
        if (t == 0) base_sh = v;
    }
    __syncthreads();
    off[b * 1024 + t] += base_sh;
    if (b == 0 && t == 0) off[n] = total;
}

// ---- scatter nodes into cluster-sorted order (unstable) ----
__global__ void k_scatter_nodes(const int* __restrict__ cl, int n, const unsigned* __restrict__ off,
                                unsigned* cur, int* __restrict__ node_sorted) {
    int i = blockIdx.x * blockDim.x + threadIdx.x;
    if (i >= n) return;
    int c = cl[i];
    unsigned slot = off[c] + atomicAdd(&cur[c], 1u);
    node_sorted[slot] = i;
}

// ---- pooled features (exact max) + mean positions; 1 wave per cluster ----
__global__ void k_pool(const float* __restrict__ x, const float* __restrict__ pos,
                       const int* __restrict__ node_sorted, const unsigned* __restrict__ off,
                       float* __restrict__ out_x, float* __restrict__ out_pos) {
    int s = blockIdx.x;
    int t = threadIdx.x;
    unsigned beg = off[s], end = off[s + 1];
    float m = -INFINITY;
    float ps = 0.f;
    for (unsigned idx = beg; idx < end; ++idx) {
        int nd = node_sorted[idx];
        m = fmaxf(m, x[(size_t)nd * F + t]);
        if (t < 2) ps += pos[(size_t)nd * 2 + t];
    }
    int cnt = (int)(end - beg);
    out_x[(size_t)s * F + t] = (cnt > 0) ? m : 0.f;
    if (t < 2) out_pos[s * 2 + t] = (cnt > 0) ? ps / (float)cnt : 0.f;
}

// ---- edge keys (r<<16|c) + histogram over r ----
__global__ void k_ehist(const int* __restrict__ ei, int e, const int* __restrict__ cl,
                        unsigned* __restrict__ keys_tmp, unsigned* __restrict__ ecnt) {
    int i = blockIdx.x * blockDim.x + threadIdx.x;
    if (i >= e) return;
    unsigned r = (unsigned)cl[ei[i]];
    unsigned c = (unsigned)cl[ei[e + i]];
    keys_tmp[i] = (r << 16) | c;
    atomicAdd(&ecnt[r], 1u);
}

// ---- scatter edges into r-bins (unstable) ----
__global__ void k_scatter_edges(const unsigned* __restrict__ keys_tmp, int e,
                                const unsigned* __restrict__ off, unsigned* cur,
                                unsigned* __restrict__ keys_sorted) {
    int i = blockIdx.x * blockDim.x + threadIdx.x;
    if (i >= e) return;
    unsigned k = keys_tmp[i];
    unsigned r = k >> 16;
    unsigned slot = off[r] + atomicAdd(&cur[r], 1u);
    keys_sorted[slot] = k;
}

// ---- sort each r-segment by full key (bitonic in LDS); 128 thr, 2KB LDS ----
__global__ void k_segsort(unsigned* keys, const unsigned* __restrict__ off) {
    __shared__ unsigned sh[SORT_CAP];
    int s = blockIdx.x;
    int beg = (int)off[s], end = (int)off[s + 1];
    int len = end - beg;
    if (len <= 1) return;
    int t = threadIdx.x;
    if (len <= SORT_CAP) {
        int P = 2; while (P < len) P <<= 1;
        for (int i = t; i < P; i += blockDim.x)
            sh[i] = (i < len) ? keys[beg + i] : 0xFFFFFFFFu;
        __syncthreads();
        for (int k = 2; k <= P; k <<= 1) {
            for (int j = k >> 1; j > 0; j >>= 1) {
                for (int i = t; i < P; i += blockDim.x) {
                    int p = i ^ j;
                    if (p > i) {
                        unsigned a = sh[i], b = sh[p];
                        bool up = ((i & k) == 0);
                        if (up ? (a > b) : (a < b)) { sh[i] = b; sh[p] = a; }
                    }
                }
                __syncthreads();
            }
        }
        for (int i = t; i < len; i += blockDim.x) keys[beg + i] = sh[i];
    } else {
        if (t == 0) {   // statistically unreachable fallback
            for (int a = beg + 1; a < end; ++a) {
                unsigned v = keys[a]; int b = a - 1;
                while (b >= beg && keys[b] > v) { keys[b + 1] = keys[b]; --b; }
                keys[b + 1] = v;
            }
        }
    }
}

// ---- flags + e_row/e_col/edge_valid outputs + per-block partial max|cart| ----
__global__ void k_eflags(const unsigned* __restrict__ keys, int e,
                         const float2* __restrict__ pos_pool,
                         float* __restrict__ out_erow, float* __restrict__ out_ecol,
                         float* __restrict__ out_valid, float* __restrict__ pmax) {
    __shared__ float shm[4];
    int i = blockIdx.x * blockDim.x + threadIdx.x;
    float am = 0.f;
    if (i < e) {
        unsigned k = keys[i];
        bool first = (i == 0) || (k != keys[i - 1]);
        unsigned r = k >> 16, c = k & 0xFFFFu;
        bool valid = first && (r != c);
        out_erow[i]  = valid ? (float)r : 0.f;
        out_ecol[i]  = valid ? (float)c : 0.f;
        out_valid[i] = valid ? 1.f : 0.f;
        if (valid) {
            float2 pr = pos_pool[r], pc = pos_pool[c];
            am = fmaxf(fabsf(pr.x - pc.x), fabsf(pr.y - pc.y));
        }
    }
    am = wave_max(am);
    int w = threadIdx.x >> 6;
    if ((threadIdx.x & 63) == 0) shm[w] = am;
    __syncthreads();
    if (threadIdx.x == 0)
        pmax[blockIdx.x] = fmaxf(fmaxf(shm[0], shm[1]), fmaxf(shm[2], shm[3]));
}

// ---- final max reduce over per-block partials: 1 block ----
__global__ void k_redmax(const float* __restrict__ pmax, int nb, unsigned* hdr) {
    __shared__ float shm[16];
    int t = threadIdx.x;
    float m = 0.f;
    for (int i = t; i < nb; i += blockDim.x) m = fmaxf(m, pmax[i]);
    m = wave_max(m);
    int w = t >> 6;
    if ((t & 63) == 0) shm[w] = m;
    __syncthreads();
    if (t == 0) {
        int nw = (blockDim.x + 63) >> 6;
        for (int i = 1; i < nw; ++i) m = fmaxf(m, shm[i]);
        hdr[2] = (unsigned)__float_as_int(m);
    }
}

// ---- edge_attr = cart / (2*max) + 0.5 ----
__global__ void k_eattr(const unsigned* __restrict__ keys, int e,
                        const float2* __restrict__ pos_pool,
                        const unsigned* __restrict__ hdr, float2* __restrict__ out_attr) {
    int i = blockIdx.x * blockDim.x + threadIdx.x;
    if (i >= e) return;
    unsigned k = keys[i];
    bool first = (i == 0) || (k != keys[i - 1]);
    unsigned r = k >> 16, c = k & 0xFFFFu;
    bool valid = first && (r != c);
    float ax = 0.f, ay = 0.f;
    if (valid) {
        float2 pr = pos_pool[r], pc = pos_pool[c];
        float denom = 2.0f * __int_as_float((int)hdr[2]);
        ax = (pr.x - pc.x) / denom + 0.5f;
        ay = (pr.y - pc.y) / denom + 0.5f;
    }
    out_attr[i] = make_float2(ax, ay);
}

extern "C" void kernel_launch(void* const* d_in, const int* in_sizes, int n_in,
                              void* d_out, int out_size, void* d_ws, size_t ws_size,
                              hipStream_t stream) {
    const float* x    = (const float*)d_in[0];
    const float* pos  = (const float*)d_in[1];
    const int* batch  = (const int*)d_in[2];
    const int* ei     = (const int*)d_in[3];
    const int n = in_sizes[2];
    const int e = in_sizes[3] / 2;

    float* out      = (float*)d_out;
    float* out_x    = out;                                   // [SEG, F]
    float* out_pos  = out_x  + (size_t)SEG * F;              // [SEG, 2]
    float* out_erow = out_pos + (size_t)SEG * 2;             // [E]
    float* out_ecol = out_erow + e;                          // [E]
    float* out_attr = out_ecol + e;                          // [E, 2]
    float* out_val  = out_attr + (size_t)2 * e;              // [E]

    const int nb_n = (n + 255) / 256;
    const int nb_e = (e + 255) / 256;

    char* w = (char*)d_ws;
    unsigned* hdr         = (unsigned*)w;                            // 3 u32 (pad 256)
    int*      cl          = (int*)(w + 256);                         // [n]
    int*      node_sorted = (int*)(w + 256 + (size_t)n * 4);         // [n]
    unsigned* node_cnt    = (unsigned*)(w + 256 + (size_t)n * 8);    // [SEG]
    unsigned* node_cur    = node_cnt + SEG;                          // [SEG]
    unsigned* ecnt        = node_cur + SEG;                          // [SEG]
    unsigned* ecur        = ecnt + SEG;                              // [SEG]
    unsigned* node_off    = ecur + SEG;                              // [SEG+1]
    unsigned* eoff        = node_off + SEG + 1;                      // [SEG+1]
    unsigned* keys_tmp    = eoff + SEG + 1;                          // [e]
    unsigned* keys_sorted = keys_tmp + e;                            // [e]
    unsigned* blksum      = keys_sorted + e;                         // [64]
    float2*   pmin        = (float2*)(blksum + 64);                  // [MINB]
    float*    pmax        = (float*)(pmin + MINB);                   // [nb_e]

    k_init<<<512, 256, 0, stream>>>(node_cnt, 4 * SEG);
    k_min<<<MINB, 256, 0, stream>>>((const float2*)pos, n, pmin);
    k_minred<<<1, 1024, 0, stream>>>(pmin, MINB, hdr);
    k_cluster<<<nb_n, 256, 0, stream>>>((const float2*)pos, batch, n, hdr, cl, node_cnt);
    k_scan1<<<64, 1024, 0, stream>>>(node_cnt, node_off, blksum);
    k_scan_add<<<64, 1024, 0, stream>>>(node_off, blksum, SEG, (unsigned)n);
    k_scatter_nodes<<<nb_n, 256, 0, stream>>>(cl, n, node_off, node_cur, node_sorted);
    k_pool<<<SEG, 64, 0, stream>>>(x, pos, node_sorted, node_off, out_x, out_pos);
    k_ehist<<<nb_e, 256, 0, stream>>>(ei, e, cl, keys_tmp, ecnt);
    k_scan1<<<64, 1024, 0, stream>>>(ecnt, eoff, blksum);
    k_scan_add<<<64, 1024, 0, stream>>>(eoff, blksum, SEG, (unsigned)e);
    k_scatter_edges<<<nb_e, 256, 0, stream>>>(keys_tmp, e, eoff, ecur, keys_sorted);
    k_segsort<<<SEG, 128, 0, stream>>>(keys_sorted, eoff);
    k_eflags<<<nb_e, 256, 0, stream>>>(keys_sorted, e, (const float2*)out_pos,
                                       out_erow, out_ecol, out_val, pmax);
    k_redmax<<<1, 1024, 0, stream>>>(pmax, nb_e, hdr);
    k_eattr<<<nb_e, 256, 0, stream>>>(keys_sorted, e, (const float2*)out_pos,
                                      hdr, (float2*)out_attr);
}